// Round 5
// baseline (223.504 us; speedup 1.0000x reference)
//
#include <hip/hip_runtime.h>

#define BB 32
#define TT 128
#define PP 512
#define DD 300
#define KP 320     // K padded: 300 data + slot 300 = bias + zeros
#define NR 13      // retained cols per pattern (tm[13] is dead)
#define NN 6656    // P * NR   (GEMM n-extent)
#define NS 7168    // P * 14   (C row stride: 14-aligned scan layout)
#define NEG -1e30f

typedef _Float16 half8 __attribute__((ext_vector_type(8)));
typedef _Float16 half4 __attribute__((ext_vector_type(4)));
typedef float floatx4 __attribute__((ext_vector_type(4)));

__device__ __forceinline__ void async_load16(const void* g, void* l) {
    __builtin_amdgcn_global_load_lds(
        (const __attribute__((address_space(1))) void*)g,
        (__attribute__((address_space(3))) void*)l, 16, 0, 0);
}

__device__ __forceinline__ floatx4 mfma16(half8 a, half8 b, floatx4 c) {
    return __builtin_amdgcn_mfma_f32_16x16x32_f16(a, b, c, 0, 0, 0);
}

// ---------------------------------------------------------------------------
// Unified pack: error-free f16 Dekker split (x = hi + lo*2^-12, lo stored
// *4096). Rows 0..4095: A = emb[tokens[m]]; rows 4096..: B = diags row
// p*14+rr (rr<13; nd1/l6 col is dead). K-slot 300 carries the bias:
// A gets exact 1.0, B gets (bias_hi, bias_lo*4096). Slots 301..319 zero.
// ---------------------------------------------------------------------------
__global__ __launch_bounds__(256) void pack_kernel(
    const int* __restrict__ tokens, const float* __restrict__ emb,
    const float* __restrict__ diags, const float* __restrict__ bias,
    _Float16* __restrict__ Ah, _Float16* __restrict__ Al,
    _Float16* __restrict__ Bh, _Float16* __restrict__ Bl)
{
    const int idx = blockIdx.x * 256 + threadIdx.x;
    if (idx >= (4096 + NN) * 80) return;
    const int r = idx / 80;
    const int c = idx - r * 80;

    float4 x = make_float4(0.f, 0.f, 0.f, 0.f);
    _Float16* dh;
    _Float16* dl;

    if (r < 4096) {
        if (c < 75) x = *(const float4*)(emb + (size_t)tokens[r] * DD + c * 4);
        else if (c == 75) x.x = 1.0f;   // bias multiplier
        dh = Ah + (size_t)r * KP + c * 4;
        dl = Al + (size_t)r * KP + c * 4;
    } else {
        const int n = r - 4096;
        const int p = n / NR;
        const int rr = n - p * NR;
        const int srow = p * 14 + rr;
        if (c < 75) x = *(const float4*)(diags + (size_t)srow * DD + c * 4);
        else if (c == 75) x.x = bias[srow];
        dh = Bh + (size_t)n * KP + c * 4;
        dl = Bl + (size_t)n * KP + c * 4;
    }

    half4 h, l;
    h.x = (_Float16)x.x; l.x = (_Float16)((x.x - (float)h.x) * 4096.f);
    h.y = (_Float16)x.y; l.y = (_Float16)((x.y - (float)h.y) * 4096.f);
    h.z = (_Float16)x.z; l.z = (_Float16)((x.z - (float)h.z) * 4096.f);
    h.w = (_Float16)x.w; l.w = (_Float16)((x.w - (float)h.w) * 4096.f);
    if (r < 4096 && c == 75) { l.x = (_Float16)0.f; }  // A bias slot: exact 1.0
    *(half4*)dh = h;
    *(half4*)dl = l;
}

// ---------------------------------------------------------------------------
// GEMM: ts[m][col(n)] = sum_k A[m][k]*B[n][k] (bias folded into k=300).
// 128x128 tile, BK=64 staged as 2x BK=32 sub-buffers, 5 K-iters.
// 3-product f16 Dekker split: acc0 = hh, acc1 = hl + lh.
// Epilogue scatters n -> col = n + n/13 (14-stride scan-friendly layout).
// ---------------------------------------------------------------------------
__global__ __launch_bounds__(256, 2) void gemm_kernel(
    const _Float16* __restrict__ Ah, const _Float16* __restrict__ Al,
    const _Float16* __restrict__ Bh, const _Float16* __restrict__ Bl,
    float* __restrict__ C)
{
    __shared__ __align__(16) _Float16 AsH[2][128 * 32];
    __shared__ __align__(16) _Float16 AsL[2][128 * 32];
    __shared__ __align__(16) _Float16 BsH[2][128 * 32];
    __shared__ __align__(16) _Float16 BsL[2][128 * 32];

    const int tid = threadIdx.x;
    const int w = tid >> 6, ln = tid & 63;
    const int n0 = blockIdx.x * 128, m0 = blockIdx.y * 128;
    const int wm = w & 1, wn = w >> 1;

    floatx4 acc0[4][4], acc1[4][4];
    #pragma unroll
    for (int i = 0; i < 4; ++i)
        #pragma unroll
        for (int j = 0; j < 4; ++j) {
            acc0[i][j] = (floatx4){0.f, 0.f, 0.f, 0.f};
            acc1[i][j] = (floatx4){0.f, 0.f, 0.f, 0.f};
        }

    const int srow = ln >> 2;       // staging: row within 16-row segment
    const int sch  = (ln & 3) * 8;  // staging: halves offset in 32-half row
    const int fr = ln & 15;         // fragment row index
    const int kg = ln >> 4;         // k-group 0..3

    // each wave stages one array (A-hi / A-lo / B-hi / B-lo)
    const _Float16* gsrc = (w == 0) ? Ah + (size_t)m0 * KP
                        : (w == 1) ? Al + (size_t)m0 * KP
                        : (w == 2) ? Bh + (size_t)n0 * KP
                                   : Bl + (size_t)n0 * KP;
    _Float16* lbase = (w == 0) ? &AsH[0][0]
                    : (w == 1) ? &AsL[0][0]
                    : (w == 2) ? &BsH[0][0]
                               : &BsL[0][0];

    for (int kt = 0; kt < KP / 64; ++kt) {
        const int k0 = kt * 64;
        #pragma unroll
        for (int kb = 0; kb < 2; ++kb) {
            #pragma unroll
            for (int s = 0; s < 8; ++s) {
                async_load16(gsrc + (size_t)(s * 16 + srow) * KP + k0 + kb * 32 + sch,
                             lbase + kb * (128 * 32) + s * 16 * 32);
            }
        }
        __syncthreads();

        #pragma unroll
        for (int kb = 0; kb < 2; ++kb) {
            half8 ah4[4], al4[4];
            #pragma unroll
            for (int i = 0; i < 4; ++i) {
                const int off = (wm * 64 + i * 16 + fr) * 32 + kg * 8;
                ah4[i] = *(const half8*)&AsH[kb][off];
                al4[i] = *(const half8*)&AsL[kb][off];
            }
            #pragma unroll
            for (int j = 0; j < 4; ++j) {
                const int off = (wn * 64 + j * 16 + fr) * 32 + kg * 8;
                const half8 bh = *(const half8*)&BsH[kb][off];
                const half8 bl = *(const half8*)&BsL[kb][off];
                #pragma unroll
                for (int i = 0; i < 4; ++i) {
                    acc0[i][j] = mfma16(ah4[i], bh, acc0[i][j]);
                    acc1[i][j] = mfma16(ah4[i], bl, acc1[i][j]);
                    acc1[i][j] = mfma16(al4[i], bh, acc1[i][j]);
                }
            }
        }
        __syncthreads();
    }

    // epilogue: C/D layout col(n)=lane&15, row(m)=(lane>>4)*4+reg
    // scatter n -> n + n/13 so each pattern's 13 values sit in a 14-slot row
    #pragma unroll
    for (int j = 0; j < 4; ++j) {
        const int n = n0 + wn * 64 + j * 16 + fr;
        const int col = n + (unsigned)n / 13u;
        #pragma unroll
        for (int i = 0; i < 4; ++i) {
            const int mb = m0 + wm * 64 + i * 16 + kg * 4;
            #pragma unroll
            for (int r = 0; r < 4; ++r)
                C[(size_t)(mb + r) * NS + col] =
                    acc0[i][j][r] + acc1[i][j][r] * (1.0f / 4096.0f);
        }
    }
}

// ---------------------------------------------------------------------------
// Max-sum scan: one thread per (b,p). 14-float rows (8B-aligned), loaded as
// 7x float2, depth-4 register prefetch (28 outstanding loads).
// v[0..6]=self-loop (diag0 l0..6), v[7..12]=main (diag1 l0..5), v[13] dead.
// ---------------------------------------------------------------------------
__global__ __launch_bounds__(64) void scan_kernel(
    const float* __restrict__ ts,
    const float* __restrict__ epsilons,
    const int* __restrict__ doc_lens,
    float* __restrict__ scores)
{
    const int b = blockIdx.x;
    const int p = blockIdx.y * 64 + threadIdx.x;
    const int dl = doc_lens[b];

    float e[6];
    #pragma unroll
    for (int i = 0; i < 6; ++i) e[i] = epsilons[p * 6 + i];

    const float* base = ts + (size_t)b * TT * NS + p * 14;

    float h0 = 0.f, h1 = NEG, h2 = NEG, h3 = NEG, h4 = NEG, h5 = NEG, h6 = NEG;
    float sc = NEG;
    const bool end5 = (p < 256);

    float2 buf[4][7];

    auto load = [&](int slot, int t) {
        const float2* s = (const float2*)(base + (size_t)t * NS);
        #pragma unroll
        for (int i = 0; i < 7; ++i) buf[slot][i] = s[i];
    };
    auto step = [&](int slot, int t) {
        const float2* v = buf[slot];
        float ae0 = h0;
        float ae1 = fmaxf(h1, h0 + e[0]);
        float ae2 = fmaxf(h2, h1 + e[1]);
        float ae3 = fmaxf(h3, h2 + e[2]);
        float ae4 = fmaxf(h4, h3 + e[3]);
        float ae5 = fmaxf(h5, h4 + e[4]);
        float ae6 = fmaxf(h6, h5 + e[5]);
        h0 = fmaxf(0.f,            ae0 + v[0].x);
        h1 = fmaxf(ae0 + v[3].y,   ae1 + v[0].y);
        h2 = fmaxf(ae1 + v[4].x,   ae2 + v[1].x);
        h3 = fmaxf(ae2 + v[4].y,   ae3 + v[1].y);
        h4 = fmaxf(ae3 + v[5].x,   ae4 + v[2].x);
        h5 = fmaxf(ae4 + v[5].y,   ae5 + v[2].y);
        h6 = fmaxf(ae5 + v[6].x,   ae6 + v[3].x);
        const float endv = end5 ? h5 : h6;
        if (t < dl) sc = fmaxf(sc, endv);
    };

    #pragma unroll
    for (int j = 0; j < 4; ++j) load(j, j);

    for (int tb = 0; tb < TT - 4; tb += 4) {
        #pragma unroll
        for (int j = 0; j < 4; ++j) {
            step(j, tb + j);
            load(j, tb + j + 4);
        }
    }
    #pragma unroll
    for (int j = 0; j < 4; ++j) step(j, TT - 4 + j);

    scores[p * BB + b] = sc;
}

// ---------------------------------------------------------------------------
// BatchNorm (batch stats) + sign(relu) + final linear. One block.
// ---------------------------------------------------------------------------
__global__ __launch_bounds__(512) void finalize_kernel(
    const float* __restrict__ scores,
    const float* __restrict__ bn_w,
    const float* __restrict__ bn_b,
    const float* __restrict__ fw,
    const float* __restrict__ fb,
    float* __restrict__ out)
{
    __shared__ float acc[64];
    const int p = threadIdx.x;
    if (p < 64) acc[p] = 0.f;
    __syncthreads();

    float x[32];
    const float4* sp = (const float4*)(scores + p * 32);
    #pragma unroll
    for (int i = 0; i < 8; ++i) ((float4*)x)[i] = sp[i];

    float mean = 0.f;
    #pragma unroll
    for (int i = 0; i < 32; ++i) mean += x[i];
    mean *= (1.f / 32.f);
    float var = 0.f;
    #pragma unroll
    for (int i = 0; i < 32; ++i) { const float d = x[i] - mean; var = fmaf(d, d, var); }
    var *= (1.f / 32.f);

    const float scale = (1.f / sqrtf(var + 1e-5f)) * bn_w[p];
    const float shift = bn_b[p];
    const float w0 = fw[p], w1 = fw[PP + p];

    for (int b = 0; b < 32; ++b) {
        const float v = (x[b] - mean) * scale + shift;
        const bool bin = v > 0.f;
        float v0 = bin ? w0 : 0.f;
        float v1 = bin ? w1 : 0.f;
        #pragma unroll
        for (int o = 32; o; o >>= 1) {
            v0 += __shfl_xor(v0, o);
            v1 += __shfl_xor(v1, o);
        }
        if ((threadIdx.x & 63) == 0) {
            atomicAdd(&acc[b * 2 + 0], v0);
            atomicAdd(&acc[b * 2 + 1], v1);
        }
    }
    __syncthreads();
    if (p < 64) out[p] = acc[p] + fb[p & 1];
}

// ---------------------------------------------------------------------------
extern "C" void kernel_launch(void* const* d_in, const int* in_sizes, int n_in,
                              void* d_out, int out_size, void* d_ws, size_t ws_size,
                              hipStream_t stream) {
    const int*   tokens   = (const int*)d_in[0];
    const int*   doc_lens = (const int*)d_in[1];
    const float* emb      = (const float*)d_in[2];
    const float* diags    = (const float*)d_in[3];
    const float* bias     = (const float*)d_in[4];
    const float* eps      = (const float*)d_in[5];
    const float* bnw      = (const float*)d_in[6];
    const float* bnb      = (const float*)d_in[7];
    const float* fw       = (const float*)d_in[8];
    const float* fb       = (const float*)d_in[9];
    float* out = (float*)d_out;

    float* ts     = (float*)d_ws;                    // [4096][7168] = 117.4 MB
    float* scores = ts + (size_t)4096 * NS;          // [512][32]
    _Float16* Ah  = (_Float16*)(scores + PP * BB);   // [4096][320]
    _Float16* Al  = Ah + (size_t)4096 * KP;
    _Float16* Bh  = Al + (size_t)4096 * KP;          // [6656][320]
    _Float16* Bl  = Bh + (size_t)NN * KP;

    pack_kernel<<<((4096 + NN) * 80 + 255) / 256, 256, 0, stream>>>(
        tokens, emb, diags, bias, Ah, Al, Bh, Bl);
    gemm_kernel<<<dim3(NN / 128, 32), 256, 0, stream>>>(Ah, Al, Bh, Bl, ts);
    scan_kernel<<<dim3(32, 8), 64, 0, stream>>>(ts, eps, doc_lens, scores);
    finalize_kernel<<<1, 512, 0, stream>>>(scores, bnw, bnb, fw, fb, out);
}